// Round 1
// 643.100 us; speedup vs baseline: 1.0105x; 1.0105x over previous
//
#include <hip/hip_runtime.h>

#define N_ROWS 200000
#define P 576
#define P4 144          // P / 4 float4 column-groups
#define GRID1 768       // 256 CUs x 3 blocks (9 waves each -> 27/32 waves/CU), zero scheduling tail
#define STRIPE (GRID1 * 8)   // 8 rows per block per iteration (2-row unroll x 4 y-slots)

// ws layout: S1[P] floats | S2[P] floats | ticket (uint)  -- all zeroed before launch

__global__ __launch_bounds__(576) void colsum_project_kernel(
    const float4* __restrict__ X4,
    const float*  __restrict__ mu,
    const float*  __restrict__ W,
    float*        __restrict__ S1,
    float*        __restrict__ S2,
    unsigned int* __restrict__ ticket,
    float*        __restrict__ out)
{
    const int x = threadIdx.x;   // [0,144): float4 column group
    const int y = threadIdx.y;   // [0,4):   row offset within 8-row block stripe

    float4 s1a = make_float4(0.f, 0.f, 0.f, 0.f);
    float4 s2a = make_float4(0.f, 0.f, 0.f, 0.f);
    float4 s1b = make_float4(0.f, 0.f, 0.f, 0.f);
    float4 s2b = make_float4(0.f, 0.f, 0.f, 0.f);

    // Block covers rows [blockIdx.x*8, blockIdx.x*8+8) each stripe; y handles r and r+4.
    for (int r = blockIdx.x * 8 + y; r < N_ROWS; r += STRIPE) {
        float4 v = X4[(size_t)r * P4 + x];
        s1a.x += v.x;  s1a.y += v.y;  s1a.z += v.z;  s1a.w += v.w;
        s2a.x = fmaf(v.x, v.x, s2a.x);
        s2a.y = fmaf(v.y, v.y, s2a.y);
        s2a.z = fmaf(v.z, v.z, s2a.z);
        s2a.w = fmaf(v.w, v.w, s2a.w);

        const int r2 = r + 4;
        if (r2 < N_ROWS) {
            float4 w = X4[(size_t)r2 * P4 + x];
            s1b.x += w.x;  s1b.y += w.y;  s1b.z += w.z;  s1b.w += w.w;
            s2b.x = fmaf(w.x, w.x, s2b.x);
            s2b.y = fmaf(w.y, w.y, s2b.y);
            s2b.z = fmaf(w.z, w.z, s2b.z);
            s2b.w = fmaf(w.w, w.w, s2b.w);
        }
    }

    s1a.x += s1b.x; s1a.y += s1b.y; s1a.z += s1b.z; s1a.w += s1b.w;
    s2a.x += s2b.x; s2a.y += s2b.y; s2a.z += s2b.z; s2a.w += s2b.w;

    __shared__ float4 sh1[4][P4];
    __shared__ float4 sh2[4][P4];
    sh1[y][x] = s1a;
    sh2[y][x] = s2a;
    __syncthreads();

    if (y == 0) {
        #pragma unroll
        for (int i = 1; i < 4; ++i) {
            float4 a = sh1[i][x], b = sh2[i][x];
            s1a.x += a.x; s1a.y += a.y; s1a.z += a.z; s1a.w += a.w;
            s2a.x += b.x; s2a.y += b.y; s2a.z += b.z; s2a.w += b.w;
        }
        atomicAdd(&S1[4 * x + 0], s1a.x);
        atomicAdd(&S1[4 * x + 1], s1a.y);
        atomicAdd(&S1[4 * x + 2], s1a.z);
        atomicAdd(&S1[4 * x + 3], s1a.w);
        atomicAdd(&S2[4 * x + 0], s2a.x);
        atomicAdd(&S2[4 * x + 1], s2a.y);
        atomicAdd(&S2[4 * x + 2], s2a.z);
        atomicAdd(&S2[4 * x + 3], s2a.w);
    }

    // ---- last-block-done ticket: the final block runs the projection ----
    __shared__ int isLast;
    __syncthreads();                       // drains this block's atomics (vmcnt 0 at barrier)
    const int tid = y * P4 + x;            // linear [0,576)
    if (tid == 0) {
        __threadfence();                   // release: our atomics visible before ticket bump
        unsigned int t = atomicAdd(ticket, 1u);
        isLast = (t == GRID1 - 1);
    }
    __syncthreads();
    if (!isLast) return;
    __threadfence();                       // acquire side

    // ---- projection: P == 576 == blockDim, one feature column per thread ----
    const float invN = 1.0f / (float)N_ROWS;
    // Agent-scope atomic loads: guaranteed coherent view of other XCDs' atomicAdds.
    float s1v = __hip_atomic_load(&S1[tid], __ATOMIC_RELAXED, __HIP_MEMORY_SCOPE_AGENT);
    float s2v = __hip_atomic_load(&S2[tid], __ATOMIC_RELAXED, __HIP_MEMORY_SCOPE_AGENT);
    float m    = s1v * invN;
    float mom2 = s2v * invN - m * m;

    const int j = 3 * tid;
    float c0 = m    - mu[j];
    float c1 = 0.f  - mu[j + 1];
    float c2 = mom2 - mu[j + 2];
    const float* w0 = &W[(size_t)j * 4];
    float acc0 = c0 * w0[0] + c1 * w0[4] + c2 * w0[8];
    float acc1 = c0 * w0[1] + c1 * w0[5] + c2 * w0[9];
    float acc2 = c0 * w0[2] + c1 * w0[6] + c2 * w0[10];
    float acc3 = c0 * w0[3] + c1 * w0[7] + c2 * w0[11];

    // wave-64 butterfly, then cross-wave LDS reduce (9 waves)
    #pragma unroll
    for (int off = 32; off > 0; off >>= 1) {
        acc0 += __shfl_down(acc0, off);
        acc1 += __shfl_down(acc1, off);
        acc2 += __shfl_down(acc2, off);
        acc3 += __shfl_down(acc3, off);
    }

    __shared__ float sacc[9][4];
    const int wave = tid >> 6;
    const int lane = tid & 63;
    if (lane == 0) {
        sacc[wave][0] = acc0;
        sacc[wave][1] = acc1;
        sacc[wave][2] = acc2;
        sacc[wave][3] = acc3;
    }
    __syncthreads();
    if (tid < 4) {
        float r = 0.f;
        #pragma unroll
        for (int i = 0; i < 9; ++i) r += sacc[i][tid];
        out[tid] = r;
    }
}

extern "C" void kernel_launch(void* const* d_in, const int* in_sizes, int n_in,
                              void* d_out, int out_size, void* d_ws, size_t ws_size,
                              hipStream_t stream) {
    const float* X  = (const float*)d_in[0];   // (200000, 576) fp32
    const float* mu = (const float*)d_in[1];   // (1728,)
    const float* W  = (const float*)d_in[2];   // (1728, 4)
    float* out = (float*)d_out;                // (4,)

    float* S1 = (float*)d_ws;
    float* S2 = S1 + P;
    unsigned int* ticket = (unsigned int*)(S2 + P);

    hipMemsetAsync(d_ws, 0, 2 * P * sizeof(float) + sizeof(unsigned int), stream);

    dim3 block(P4, 4);  // 576 threads = 9 waves
    colsum_project_kernel<<<GRID1, block, 0, stream>>>((const float4*)X, mu, W,
                                                       S1, S2, ticket, out);
}